// Round 1
// baseline (1126.555 us; speedup 1.0000x reference)
//
#include <hip/hip_runtime.h>
#include <math.h>

#define NTHREADS 256

// ---------------------------------------------------------------------------
// spconv64: out[n,d] = sum_{k in [kb0,kb1)} sum_c feat[nmap[n,k], c] * W[k,c,d]
// 64 output rows per block (x), tap-chunk per block (y). No bias/relu here.
// ---------------------------------------------------------------------------
__global__ __launch_bounds__(256) void spconv64(
    const float* __restrict__ feat, const int* __restrict__ nmap,
    const float* __restrict__ W, float* __restrict__ out,
    int Nout, int K, int atomic_mode)
{
    __shared__ float featl[64][68];   // padded to avoid bank conflicts
    __shared__ float Wl[64 * 64];     // W[k][c][d] slice, c-major
    __shared__ int   jl[27 * 64];     // gather indices, tap-major

    const int t = threadIdx.x;
    const int row0 = blockIdx.x * 64;
    const int nchunk = gridDim.y;
    const int per = (K + nchunk - 1) / nchunk;
    const int kb0 = blockIdx.y * per;
    const int kb1 = min(K, kb0 + per);
    const int nk = kb1 - kb0;

    for (int i = t; i < nk * 64; i += NTHREADS) {
        int k = i >> 6, r = i & 63;
        jl[i] = nmap[(size_t)(row0 + r) * K + (kb0 + k)];
    }

    float acc[4][4] = {};
    const int tx = t & 15;      // output cols tx*4 .. tx*4+3
    const int ry = t >> 4;      // output rows ry*4 .. ry*4+3

    for (int k = 0; k < nk; ++k) {
        __syncthreads();  // previous tile fully consumed; jl visible (iter 0)
        // stage W[kb0+k][64][64] (16 KB)
        {
            const float4* Wk4 = (const float4*)(W + (size_t)(kb0 + k) * 4096);
            float4* Wl4 = (float4*)Wl;
#pragma unroll
            for (int i = 0; i < 4; ++i) Wl4[t + i * 256] = Wk4[t + i * 256];
        }
        // stage gathered feature rows (64 x 64 floats)
        {
            int r = t >> 2, q = t & 3;
            int j = jl[k * 64 + r];
            const float4* src = (const float4*)(feat + (size_t)j * 64) + q * 4;
            float4* dst = (float4*)&featl[r][q * 16];
            dst[0] = src[0]; dst[1] = src[1]; dst[2] = src[2]; dst[3] = src[3];
        }
        __syncthreads();
#pragma unroll 8
        for (int c = 0; c < 64; ++c) {
            float4 b = *(const float4*)&Wl[c * 64 + tx * 4];
            float a0 = featl[ry * 4 + 0][c];
            float a1 = featl[ry * 4 + 1][c];
            float a2 = featl[ry * 4 + 2][c];
            float a3 = featl[ry * 4 + 3][c];
            acc[0][0] += a0 * b.x; acc[0][1] += a0 * b.y; acc[0][2] += a0 * b.z; acc[0][3] += a0 * b.w;
            acc[1][0] += a1 * b.x; acc[1][1] += a1 * b.y; acc[1][2] += a1 * b.z; acc[1][3] += a1 * b.w;
            acc[2][0] += a2 * b.x; acc[2][1] += a2 * b.y; acc[2][2] += a2 * b.z; acc[2][3] += a2 * b.w;
            acc[3][0] += a3 * b.x; acc[3][1] += a3 * b.y; acc[3][2] += a3 * b.z; acc[3][3] += a3 * b.w;
        }
    }

#pragma unroll
    for (int i = 0; i < 4; ++i) {
        int row = row0 + ry * 4 + i;
        float* o = out + (size_t)row * 64 + tx * 4;
        if (!atomic_mode) {
            float4 v = {acc[i][0], acc[i][1], acc[i][2], acc[i][3]};
            *(float4*)o = v;
        } else {
            atomicAdd(o + 0, acc[i][0]);
            atomicAdd(o + 1, acc[i][1]);
            atomicAdd(o + 2, acc[i][2]);
            atomicAdd(o + 3, acc[i][3]);
        }
    }
}

// ---------------------------------------------------------------------------
// epi_relu: buf = relu(buf + bias[c])  (elementwise over [N,64])
// ---------------------------------------------------------------------------
__global__ void epi_relu(float* buf, const float* __restrict__ bias, int n64)
{
    int i = blockIdx.x * blockDim.x + threadIdx.x;
    int stride = gridDim.x * blockDim.x;
    for (; i < n64; i += stride) buf[i] = fmaxf(buf[i] + bias[i & 63], 0.f);
}

// ---------------------------------------------------------------------------
// epi_full: t = (bconv ? relu(src+bconv) : src);
//           hx = t@Wout + bout  -> hx_out;
//           g  = sigmoid(hx@Wg + bg);  dst = g * t
// One wave per row. Grid must satisfy N % (gridDim.x*4) == 0 (always 256 blocks).
// ---------------------------------------------------------------------------
__global__ __launch_bounds__(256) void epi_full(
    const float* __restrict__ src, float* __restrict__ dst,
    const float* __restrict__ bconv,
    const float* __restrict__ Wout, const float* __restrict__ bout,
    const float* __restrict__ Wg, const float* __restrict__ bg,
    float* __restrict__ hx_out, int N)
{
    __shared__ float Woutl[64 * 32];
    __shared__ float Wgl[32 * 64];
    __shared__ float boutl[32];
    __shared__ float bgl[64];
    __shared__ float tl[4][64];
    __shared__ float hxl[4][32];

    const int t = threadIdx.x;
    for (int i = t; i < 64 * 32; i += NTHREADS) Woutl[i] = Wout[i];
    for (int i = t; i < 32 * 64; i += NTHREADS) Wgl[i] = Wg[i];
    if (t < 32) boutl[t] = bout[t];
    if (t >= 64 && t < 128) bgl[t - 64] = bg[t - 64];
    __syncthreads();

    const int wid = t >> 6, lane = t & 63;
    const int nw = gridDim.x * 4;
    for (int row = blockIdx.x * 4 + wid; row < N; row += nw) {
        float v = src[(size_t)row * 64 + lane];
        float tc = bconv ? fmaxf(v + bconv[lane], 0.f) : v;
        __syncthreads();          // prior iter's hxl/tl reads complete
        tl[wid][lane] = tc;
        __syncthreads();
        int d = lane & 31;
        float hx = boutl[d];
#pragma unroll 8
        for (int c = 0; c < 64; ++c) hx += tl[wid][c] * Woutl[c * 32 + d];
        if (lane < 32) {
            hx_out[(size_t)row * 32 + lane] = hx;
            hxl[wid][lane] = hx;
        }
        __syncthreads();
        float g = bgl[lane];
#pragma unroll 8
        for (int dd = 0; dd < 32; ++dd) g += hxl[wid][dd] * Wgl[dd * 64 + lane];
        g = 1.f / (1.f + __expf(-g));
        dst[(size_t)row * 64 + lane] = g * tc;
    }
}

// ---------------------------------------------------------------------------
extern "C" void kernel_launch(void* const* d_in, const int* in_sizes, int n_in,
                              void* d_out, int out_size, void* d_ws, size_t ws_size,
                              hipStream_t stream)
{
    const float* x    = (const float*)d_in[0];
    const float* Wg0  = (const float*)d_in[1];
    const float* bg0  = (const float*)d_in[2];
    const float* Wg1  = (const float*)d_in[3];
    const float* bg1  = (const float*)d_in[4];
    const float* Wout = (const float*)d_in[5];
    const float* bout = (const float*)d_in[6];
    const float* WA   = (const float*)d_in[7];
    const float* bA   = (const float*)d_in[8];
    const float* WB   = (const float*)d_in[9];
    const float* bB   = (const float*)d_in[10];
    const float* WD   = (const float*)d_in[11];
    const float* bD   = (const float*)d_in[12];
    const float* WC   = (const float*)d_in[13];
    const float* bC   = (const float*)d_in[14];
    const int* nmap[4] = {(const int*)d_in[15], (const int*)d_in[16],
                          (const int*)d_in[17], (const int*)d_in[18]};
    const int* ndm[3]  = {(const int*)d_in[19], (const int*)d_in[20],
                          (const int*)d_in[21]};

    float* out = (float*)d_out;
    float* bufA = (float*)d_ws;
    float* bufB = bufA + (size_t)65536 * 64;

    const int Ns[4] = {65536, 16384, 4096, 1024};
    size_t off[7];
    off[0] = 0;
    off[1] = off[0] + (size_t)65536 * 32;
    off[2] = off[1] + (size_t)65536 * 32;
    off[3] = off[2] + (size_t)16384 * 32;
    off[4] = off[3] + (size_t)16384 * 32;
    off[5] = off[4] + (size_t)4096 * 32;
    off[6] = off[5] + (size_t)4096 * 32;

    auto conv = [&](const float* fin, const int* nm, const float* W, float* o,
                    int Nout, int K, int chunks) {
        if (chunks > 1) hipMemsetAsync(o, 0, (size_t)Nout * 64 * sizeof(float), stream);
        dim3 grid(Nout / 64, chunks);
        hipLaunchKernelGGL(spconv64, grid, dim3(NTHREADS), 0, stream,
                           fin, nm, W, o, Nout, K, chunks > 1 ? 1 : 0);
    };

    // init: hx0 = x@Wout+bout -> out0 ; cxg0 = sigmoid(hx0@Wg0+bg0)*x -> bufA
    hipLaunchKernelGGL(epi_full, dim3(256), dim3(NTHREADS), 0, stream,
                       x, bufA, (const float*)nullptr, Wout, bout, Wg0, bg0,
                       out + off[0], Ns[0]);

    for (int s = 0; s < 3; ++s) {
        int N = Ns[s], Nn = Ns[s + 1];
        int ch_ab = (N / 64 >= 128) ? 1 : 4;              // A,B at N rows
        int ch_d  = (Nn / 64 >= 128) ? 1 : (Nn == 4096 ? 4 : 8);
        int ch_c  = (Nn / 64 >= 128) ? 1 : (Nn == 4096 ? 4 : 14);

        // sub-step 0: convA, convB (+fused hx/gate epilogue with Wg1)
        conv(bufA, nmap[s], WA, bufB, N, 27, ch_ab);
        hipLaunchKernelGGL(epi_relu, dim3(256), dim3(NTHREADS), 0, stream,
                           bufB, bA, N * 64);
        conv(bufB, nmap[s], WB, bufA, N, 27, ch_ab);
        hipLaunchKernelGGL(epi_full, dim3(256), dim3(NTHREADS), 0, stream,
                           bufA, bufA, bB, Wout, bout, Wg1, bg1,
                           out + off[s * 2 + 1], N);

        // sub-step 1: convD (downsample), convC (+fused epilogue with Wg0 for next stage)
        conv(bufA, ndm[s], WD, bufB, Nn, 8, ch_d);
        hipLaunchKernelGGL(epi_relu, dim3(256), dim3(NTHREADS), 0, stream,
                           bufB, bD, Nn * 64);
        conv(bufB, nmap[s + 1], WC, bufA, Nn, 27, ch_c);
        hipLaunchKernelGGL(epi_full, dim3(256), dim3(NTHREADS), 0, stream,
                           bufA, bufA, bC, Wout, bout, Wg0, bg0,
                           out + off[s * 2 + 2], Nn);
    }
}

// Round 2
// 638.621 us; speedup vs baseline: 1.7640x; 1.7640x over previous
//
#include <hip/hip_runtime.h>
#include <hip/hip_bf16.h>

typedef __attribute__((ext_vector_type(8))) short short8;
typedef __attribute__((ext_vector_type(4))) float f32x4;

#define N0 65536
#define N1 16384
#define N2 4096
#define N3 1024

// ---------------------------------------------------------------------------
// Weight prep: Wt[k][d][c] = bf16(W[k][c][d])   (total = K*4096 elements)
// ---------------------------------------------------------------------------
__global__ void prep_w(const float* __restrict__ W, __hip_bfloat16* __restrict__ Wt,
                       int total)
{
    int i = blockIdx.x * 256 + threadIdx.x;
    if (i >= total) return;
    int k = i >> 12, r = i & 4095, d = r >> 6, c = r & 63;
    Wt[i] = __float2bfloat16(W[(k << 12) + (c << 6) + d]);
}

// ---------------------------------------------------------------------------
// MFMA sparse conv: out[n,d] = sum_k sum_c feat[nmap[n,k],c] * W[k][c][d]
// feat bf16 [Nin][64]; Wt bf16 [K][d][c]; 64 output rows/block, 4 waves.
// mode 0: store bf16 raw; mode 1: atomicAdd f32 (tap-split); mode 2: bf16 bias+relu
// LDS XOR-swizzle: 16B-block q of row r holds global block q^(r&7) (rule #21:
// inverse-swizzled per-lane global source + swizzled ds_read, linear LDS dest).
// ---------------------------------------------------------------------------
__global__ __launch_bounds__(256) void spconv_mfma(
    const __hip_bfloat16* __restrict__ feat, const int* __restrict__ nmap,
    const __hip_bfloat16* __restrict__ Wt, void* __restrict__ outp,
    const float* __restrict__ bias, int Nout, int K, int mode)
{
    __shared__ short Abuf[2][64 * 64];
    __shared__ short Bbuf[2][64 * 64];
    __shared__ int jl[28 * 64];

    const int t = threadIdx.x;
    const int w = t >> 6, l = t & 63;
    const int row0 = blockIdx.x * 64;
    const int per = (K + gridDim.y - 1) / gridDim.y;
    const int kb0 = blockIdx.y * per;
    const int nk = min(K, kb0 + per) - kb0;

    for (int i = t; i < nk * 64; i += 256) {
        int k = i >> 6, r = i & 63;
        jl[i] = nmap[(size_t)(row0 + r) * K + (kb0 + k)];
    }
    __syncthreads();

    // staging geometry: slot = w*128 + i*64 + l ; r = slot>>3, q = slot&7
    const int rr0 = (w << 4) + (l >> 3);        // i=0 row, +8 for i=1
    const int qq = (l & 7) ^ (l >> 3);          // inverse-swizzled 16B block

    auto stage = [&](int buf, int k) {
        const __hip_bfloat16* Wk = Wt + (size_t)(kb0 + k) * 4096;
#pragma unroll
        for (int i = 0; i < 2; ++i) {
            int rr = rr0 + (i << 3);
            int j = jl[(k << 6) + rr];
            const __hip_bfloat16* asrc = feat + ((size_t)j << 6) + (qq << 3);
            __builtin_amdgcn_global_load_lds(
                (const __attribute__((address_space(1))) void*)asrc,
                (__attribute__((address_space(3))) void*)&Abuf[buf][(w << 10) + (i << 9)],
                16, 0, 0);
            const __hip_bfloat16* bsrc = Wk + (rr << 6) + (qq << 3);
            __builtin_amdgcn_global_load_lds(
                (const __attribute__((address_space(1))) void*)bsrc,
                (__attribute__((address_space(3))) void*)&Bbuf[buf][(w << 10) + (i << 9)],
                16, 0, 0);
        }
    };

    f32x4 acc[4] = {};
    const int lr = l & 15, lh = l >> 4;

    stage(0, 0);
    asm volatile("s_waitcnt vmcnt(0)" ::: "memory");
    __syncthreads();

    int cur = 0;
    for (int k = 0; k < nk; ++k) {
        if (k + 1 < nk) stage(cur ^ 1, k + 1);
        const short* Ab = Abuf[cur];
        const short* Bb = Bbuf[cur];
        const int arow = (w << 4) + lr;
#pragma unroll
        for (int kk = 0; kk < 2; ++kk) {
            int q = (kk << 2) + lh;
            short8 a = *(const short8*)&Ab[(arow << 6) + ((q ^ (arow & 7)) << 3)];
#pragma unroll
            for (int ct = 0; ct < 4; ++ct) {
                int drow = (ct << 4) + lr;
                short8 b = *(const short8*)&Bb[(drow << 6) + ((q ^ (drow & 7)) << 3)];
                acc[ct] = __builtin_amdgcn_mfma_f32_16x16x32_bf16(a, b, acc[ct], 0, 0, 0);
            }
        }
        asm volatile("s_waitcnt vmcnt(0)" ::: "memory");
        __syncthreads();
        cur ^= 1;
    }

    // epilogue: C/D layout col = lane&15 (+ct*16), row = (lane>>4)*4 + reg
    if (mode == 1) {
        float* o32 = (float*)outp;
#pragma unroll
        for (int ct = 0; ct < 4; ++ct)
#pragma unroll
            for (int r = 0; r < 4; ++r) {
                int row = row0 + (w << 4) + (lh << 2) + r;
                int col = (ct << 4) + lr;
                atomicAdd(&o32[((size_t)row << 6) + col], acc[ct][r]);
            }
    } else {
        __hip_bfloat16* ob = (__hip_bfloat16*)outp;
#pragma unroll
        for (int ct = 0; ct < 4; ++ct) {
            int col = (ct << 4) + lr;
            float bv = (mode == 2) ? bias[col] : 0.f;
#pragma unroll
            for (int r = 0; r < 4; ++r) {
                int row = row0 + (w << 4) + (lh << 2) + r;
                float v = acc[ct][r];
                if (mode == 2) v = fmaxf(v + bv, 0.f);
                ob[((size_t)row << 6) + col] = __float2bfloat16(v);
            }
        }
    }
}

// ---------------------------------------------------------------------------
// epi_relu_bf: out_bf16 = relu(in_f32 + bias[c])  over [N][64]
// ---------------------------------------------------------------------------
__global__ void epi_relu_bf(const float* __restrict__ in, const float* __restrict__ bias,
                            __hip_bfloat16* __restrict__ outb, int nv /* = N*16 */)
{
    int i = blockIdx.x * blockDim.x + threadIdx.x;
    if (i >= nv) return;
    float4 v = ((const float4*)in)[i];
    int c = (i << 2) & 63;
    ushort4 o;
    o.x = __builtin_bit_cast(unsigned short, __float2bfloat16(fmaxf(v.x + bias[c + 0], 0.f)));
    o.y = __builtin_bit_cast(unsigned short, __float2bfloat16(fmaxf(v.y + bias[c + 1], 0.f)));
    o.z = __builtin_bit_cast(unsigned short, __float2bfloat16(fmaxf(v.z + bias[c + 2], 0.f)));
    o.w = __builtin_bit_cast(unsigned short, __float2bfloat16(fmaxf(v.w + bias[c + 3], 0.f)));
    ((ushort4*)outb)[i] = o;
}

// ---------------------------------------------------------------------------
// epi_full: t = act(src); hx = t@Wout + bout -> hx_out (f32);
//           g = sigmoid(hx@Wg + bg); gout = bf16(g*t)
// One thread per row, no LDS, no barriers; weights via uniform scalar loads.
// smode 0: src bf16 + bias + relu; 1: src f32 + bias + relu; 2: src f32 raw.
// ---------------------------------------------------------------------------
__global__ __launch_bounds__(256) void epi_full(
    const void* __restrict__ srcp, int smode, const float* __restrict__ bconv,
    const float* __restrict__ Wout, const float* __restrict__ bout,
    const float* __restrict__ Wg, const float* __restrict__ bg,
    float* __restrict__ hx_out, __hip_bfloat16* __restrict__ gout, int N)
{
    const int row = blockIdx.x * 256 + threadIdx.x;
    if (row >= N) return;

    const __hip_bfloat16* sb = (const __hip_bfloat16*)srcp + ((size_t)row << 6);
    const float* sf = (const float*)srcp + ((size_t)row << 6);

    // act(src) chunk loader: 4 consecutive channels starting at c0 (c0 = 4*cc)
    auto load4 = [&](int cc, float* o) {
        int c0 = cc << 2;
        if (smode == 0) {
            ushort4 v = ((const ushort4*)sb)[cc];
            o[0] = __bfloat162float(__builtin_bit_cast(__hip_bfloat16, v.x));
            o[1] = __bfloat162float(__builtin_bit_cast(__hip_bfloat16, v.y));
            o[2] = __bfloat162float(__builtin_bit_cast(__hip_bfloat16, v.z));
            o[3] = __bfloat162float(__builtin_bit_cast(__hip_bfloat16, v.w));
        } else {
            float4 v = ((const float4*)sf)[cc];
            o[0] = v.x; o[1] = v.y; o[2] = v.z; o[3] = v.w;
        }
        if (smode != 2) {
#pragma unroll
            for (int j = 0; j < 4; ++j) o[j] = fmaxf(o[j] + bconv[c0 + j], 0.f);
        }
    };

    // hx = t @ Wout + bout   (64x32), hx static-indexed
    float hx[32];
#pragma unroll
    for (int d = 0; d < 32; ++d) hx[d] = bout[d];
    for (int cc = 0; cc < 16; ++cc) {
        float tc[4];
        load4(cc, tc);
        const float* wrow = Wout + (cc << 7);   // 4 rows of 32
#pragma unroll
        for (int ci = 0; ci < 4; ++ci)
#pragma unroll
            for (int d = 0; d < 32; ++d)
                hx[d] = fmaf(tc[ci], wrow[(ci << 5) + d], hx[d]);
    }
    {
        float* ho = hx_out + ((size_t)row << 5);
#pragma unroll
        for (int i = 0; i < 8; ++i) {
            float4 v = {hx[i * 4 + 0], hx[i * 4 + 1], hx[i * 4 + 2], hx[i * 4 + 3]};
            ((float4*)ho)[i] = v;
        }
    }

    // g = sigmoid(hx @ Wg + bg); gout = bf16(g * t) in 16-wide chunks
    __hip_bfloat16* go = gout + ((size_t)row << 6);
    for (int jc = 0; jc < 4; ++jc) {
        float acc[16];
#pragma unroll
        for (int jj = 0; jj < 16; ++jj) acc[jj] = bg[(jc << 4) + jj];
#pragma unroll
        for (int d = 0; d < 32; ++d) {
            float hd = hx[d];
            const float* wr = Wg + (d << 6) + (jc << 4);
#pragma unroll
            for (int jj = 0; jj < 16; ++jj) acc[jj] = fmaf(hd, wr[jj], acc[jj]);
        }
        unsigned short ob[16];
#pragma unroll
        for (int jj = 0; jj < 16; ++jj) {
            int j = (jc << 4) + jj;
            float tv4[4];
            if ((jj & 3) == 0) {} // t reload in 4-chunks below
            // reload t[j] (cheap, L1-hot)
            float tj;
            if (smode == 0) tj = __bfloat162float(sb[j]);
            else tj = sf[j];
            if (smode != 2) tj = fmaxf(tj + bconv[j], 0.f);
            float gg = 1.f / (1.f + __expf(-acc[jj]));
            ob[jj] = __builtin_bit_cast(unsigned short, __float2bfloat16(gg * tj));
            (void)tv4;
        }
#pragma unroll
        for (int i = 0; i < 2; ++i) {
            ushort4 v0 = {ob[i * 8 + 0], ob[i * 8 + 1], ob[i * 8 + 2], ob[i * 8 + 3]};
            ushort4 v1 = {ob[i * 8 + 4], ob[i * 8 + 5], ob[i * 8 + 6], ob[i * 8 + 7]};
            ((ushort4*)go)[(jc << 2) + i * 2 + 0] = v0;
            ((ushort4*)go)[(jc << 2) + i * 2 + 1] = v1;
        }
    }
}

// ---------------------------------------------------------------------------
extern "C" void kernel_launch(void* const* d_in, const int* in_sizes, int n_in,
                              void* d_out, int out_size, void* d_ws, size_t ws_size,
                              hipStream_t stream)
{
    const float* x    = (const float*)d_in[0];
    const float* Wg0  = (const float*)d_in[1];
    const float* bg0  = (const float*)d_in[2];
    const float* Wg1  = (const float*)d_in[3];
    const float* bg1  = (const float*)d_in[4];
    const float* Wout = (const float*)d_in[5];
    const float* bout = (const float*)d_in[6];
    const float* WA   = (const float*)d_in[7];
    const float* bA   = (const float*)d_in[8];
    const float* WB   = (const float*)d_in[9];
    const float* bB   = (const float*)d_in[10];
    const float* WD   = (const float*)d_in[11];
    const float* bD   = (const float*)d_in[12];
    const float* WC   = (const float*)d_in[13];
    const float* bC   = (const float*)d_in[14];
    const int* nmap[4] = {(const int*)d_in[15], (const int*)d_in[16],
                          (const int*)d_in[17], (const int*)d_in[18]};
    const int* ndm[3]  = {(const int*)d_in[19], (const int*)d_in[20],
                          (const int*)d_in[21]};

    float* out = (float*)d_out;
    __hip_bfloat16* featbf0 = (__hip_bfloat16*)d_ws;
    __hip_bfloat16* featbf1 = featbf0 + (size_t)N0 * 64;
    __hip_bfloat16* convbf  = featbf1 + (size_t)N0 * 64;
    float* conv32 = (float*)(convbf + (size_t)N0 * 64);
    __hip_bfloat16* WAt = (__hip_bfloat16*)(conv32 + (size_t)N2 * 64);
    __hip_bfloat16* WBt = WAt + 27 * 4096;
    __hip_bfloat16* WCt = WBt + 27 * 4096;
    __hip_bfloat16* WDt = WCt + 27 * 4096;

    const int Ns[4] = {N0, N1, N2, N3};
    size_t off[7];
    off[0] = 0;
    off[1] = off[0] + (size_t)N0 * 32;
    off[2] = off[1] + (size_t)N0 * 32;
    off[3] = off[2] + (size_t)N1 * 32;
    off[4] = off[3] + (size_t)N1 * 32;
    off[5] = off[4] + (size_t)N2 * 32;
    off[6] = off[5] + (size_t)N2 * 32;

    hipLaunchKernelGGL(prep_w, dim3((27 * 4096 + 255) / 256), dim3(256), 0, stream, WA, WAt, 27 * 4096);
    hipLaunchKernelGGL(prep_w, dim3((27 * 4096 + 255) / 256), dim3(256), 0, stream, WB, WBt, 27 * 4096);
    hipLaunchKernelGGL(prep_w, dim3((27 * 4096 + 255) / 256), dim3(256), 0, stream, WC, WCt, 27 * 4096);
    hipLaunchKernelGGL(prep_w, dim3((8 * 4096 + 255) / 256), dim3(256), 0, stream, WD, WDt, 8 * 4096);

    // returns consumer smode: 0 -> bf16 result in dst_bf/mode, 1 -> f32 in conv32
    auto run_conv = [&](const __hip_bfloat16* fin, const int* nm,
                        const __hip_bfloat16* Wt, int Nout, int K,
                        const float* bias2, void* bf_dst, int big_mode) -> int {
        if (Nout >= 16384) {
            hipLaunchKernelGGL(spconv_mfma, dim3(Nout / 64, 1), dim3(256), 0, stream,
                               fin, nm, Wt, bf_dst, bias2, Nout, K, big_mode);
            return 0;
        }
        int ch = (Nout == 4096) ? (K == 27 ? 4 : 2) : (K == 27 ? 7 : 4);
        hipMemsetAsync(conv32, 0, (size_t)Nout * 64 * sizeof(float), stream);
        hipLaunchKernelGGL(spconv_mfma, dim3(Nout / 64, ch), dim3(256), 0, stream,
                           fin, nm, Wt, conv32, (const float*)nullptr, Nout, K, 1);
        return 1;
    };

    // init: hx0 -> out0 ; featbf0 = bf16(sigmoid(hx0@Wg0+bg0) * x)
    hipLaunchKernelGGL(epi_full, dim3(N0 / 256), dim3(256), 0, stream,
                       (const void*)x, 2, (const float*)nullptr, Wout, bout, Wg0, bg0,
                       out + off[0], featbf0, N0);

    for (int s = 0; s < 3; ++s) {
        int N = Ns[s], Nn = Ns[s + 1];

        // conv A: featbf0 -> featbf1 (bias+relu fused when big)
        int mA = run_conv(featbf0, nmap[s], WAt, N, 27, bA, featbf1, 2);
        if (mA == 1)
            hipLaunchKernelGGL(epi_relu_bf, dim3((N * 16 + 255) / 256), dim3(256), 0, stream,
                               conv32, bA, featbf1, N * 16);
        // conv B: featbf1 -> raw (convbf or conv32)
        int mB = run_conv(featbf1, nmap[s], WBt, N, 27, nullptr, convbf, 0);
        hipLaunchKernelGGL(epi_full, dim3(N / 256), dim3(256), 0, stream,
                           mB ? (const void*)conv32 : (const void*)convbf, mB, bB,
                           Wout, bout, Wg1, bg1, out + off[s * 2 + 1], featbf0, N);

        // conv D: featbf0 (nd map, K=8) -> featbf1
        int mD = run_conv(featbf0, ndm[s], WDt, Nn, 8, bD, featbf1, 2);
        if (mD == 1)
            hipLaunchKernelGGL(epi_relu_bf, dim3((Nn * 16 + 255) / 256), dim3(256), 0, stream,
                               conv32, bD, featbf1, Nn * 16);
        // conv C: featbf1 -> raw
        int mC = run_conv(featbf1, nmap[s + 1], WCt, Nn, 27, nullptr, convbf, 0);
        hipLaunchKernelGGL(epi_full, dim3(Nn / 256), dim3(256), 0, stream,
                           mC ? (const void*)conv32 : (const void*)convbf, mC, bC,
                           Wout, bout, Wg0, bg0, out + off[s * 2 + 2], featbf0, Nn);
    }
}

// Round 3
// 345.757 us; speedup vs baseline: 3.2582x; 1.8470x over previous
//
#include <hip/hip_runtime.h>
#include <hip/hip_bf16.h>

typedef __attribute__((ext_vector_type(8))) short short8;
typedef __attribute__((ext_vector_type(4))) float f32x4;

#define N0 65536
#define N1 16384
#define N2 4096
#define N3 1024

// ---------------------------------------------------------------------------
// Weight prep (all 4 tensors in one launch; dst buffers contiguous):
// Wt[k][d][c] = bf16(W[k][c][d])
// ---------------------------------------------------------------------------
__global__ void prep_w4(const float* __restrict__ A, const float* __restrict__ B,
                        const float* __restrict__ C, const float* __restrict__ D,
                        __hip_bfloat16* __restrict__ dst, int total)
{
    int i = blockIdx.x * 256 + threadIdx.x;
    if (i >= total) return;
    int k = i >> 12, r = i & 4095, d = r >> 6, c = r & 63;
    const float* src; int kl;
    if (k < 27)      { src = A; kl = k; }
    else if (k < 54) { src = B; kl = k - 27; }
    else if (k < 81) { src = C; kl = k - 54; }
    else             { src = D; kl = k - 81; }
    dst[i] = __float2bfloat16(src[(kl << 12) + (c << 6) + d]);
}

// ---------------------------------------------------------------------------
// MFMA sparse conv (unchanged from round 2)
// ---------------------------------------------------------------------------
__global__ __launch_bounds__(256) void spconv_mfma(
    const __hip_bfloat16* __restrict__ feat, const int* __restrict__ nmap,
    const __hip_bfloat16* __restrict__ Wt, void* __restrict__ outp,
    const float* __restrict__ bias, int Nout, int K, int mode)
{
    __shared__ short Abuf[2][64 * 64];
    __shared__ short Bbuf[2][64 * 64];
    __shared__ int jl[28 * 64];

    const int t = threadIdx.x;
    const int w = t >> 6, l = t & 63;
    const int row0 = blockIdx.x * 64;
    const int per = (K + gridDim.y - 1) / gridDim.y;
    const int kb0 = blockIdx.y * per;
    const int nk = min(K, kb0 + per) - kb0;

    for (int i = t; i < nk * 64; i += 256) {
        int k = i >> 6, r = i & 63;
        jl[i] = nmap[(size_t)(row0 + r) * K + (kb0 + k)];
    }
    __syncthreads();

    const int rr0 = (w << 4) + (l >> 3);
    const int qq = (l & 7) ^ (l >> 3);

    auto stage = [&](int buf, int k) {
        const __hip_bfloat16* Wk = Wt + (size_t)(kb0 + k) * 4096;
#pragma unroll
        for (int i = 0; i < 2; ++i) {
            int rr = rr0 + (i << 3);
            int j = jl[(k << 6) + rr];
            const __hip_bfloat16* asrc = feat + ((size_t)j << 6) + (qq << 3);
            __builtin_amdgcn_global_load_lds(
                (const __attribute__((address_space(1))) void*)asrc,
                (__attribute__((address_space(3))) void*)&Abuf[buf][(w << 10) + (i << 9)],
                16, 0, 0);
            const __hip_bfloat16* bsrc = Wk + (rr << 6) + (qq << 3);
            __builtin_amdgcn_global_load_lds(
                (const __attribute__((address_space(1))) void*)bsrc,
                (__attribute__((address_space(3))) void*)&Bbuf[buf][(w << 10) + (i << 9)],
                16, 0, 0);
        }
    };

    f32x4 acc[4] = {};
    const int lr = l & 15, lh = l >> 4;

    stage(0, 0);
    asm volatile("s_waitcnt vmcnt(0)" ::: "memory");
    __syncthreads();

    int cur = 0;
    for (int k = 0; k < nk; ++k) {
        if (k + 1 < nk) stage(cur ^ 1, k + 1);
        const short* Ab = Abuf[cur];
        const short* Bb = Bbuf[cur];
        const int arow = (w << 4) + lr;
#pragma unroll
        for (int kk = 0; kk < 2; ++kk) {
            int q = (kk << 2) + lh;
            short8 a = *(const short8*)&Ab[(arow << 6) + ((q ^ (arow & 7)) << 3)];
#pragma unroll
            for (int ct = 0; ct < 4; ++ct) {
                int drow = (ct << 4) + lr;
                short8 b = *(const short8*)&Bb[(drow << 6) + ((q ^ (drow & 7)) << 3)];
                acc[ct] = __builtin_amdgcn_mfma_f32_16x16x32_bf16(a, b, acc[ct], 0, 0, 0);
            }
        }
        asm volatile("s_waitcnt vmcnt(0)" ::: "memory");
        __syncthreads();
        cur ^= 1;
    }

    if (mode == 1) {
        float* o32 = (float*)outp;
#pragma unroll
        for (int ct = 0; ct < 4; ++ct)
#pragma unroll
            for (int r = 0; r < 4; ++r) {
                int row = row0 + (w << 4) + (lh << 2) + r;
                int col = (ct << 4) + lr;
                atomicAdd(&o32[((size_t)row << 6) + col], acc[ct][r]);
            }
    } else {
        __hip_bfloat16* ob = (__hip_bfloat16*)outp;
#pragma unroll
        for (int ct = 0; ct < 4; ++ct) {
            int col = (ct << 4) + lr;
            float bv = (mode == 2) ? bias[col] : 0.f;
#pragma unroll
            for (int r = 0; r < 4; ++r) {
                int row = row0 + (w << 4) + (lh << 2) + r;
                float v = acc[ct][r];
                if (mode == 2) v = fmaxf(v + bv, 0.f);
                ob[((size_t)row << 6) + col] = __float2bfloat16(v);
            }
        }
    }
}

// ---------------------------------------------------------------------------
// epi_relu_bf: out_bf16 = relu(in_f32 + bias[c])  over [N][64]
// ---------------------------------------------------------------------------
__global__ void epi_relu_bf(const float* __restrict__ in, const float* __restrict__ bias,
                            __hip_bfloat16* __restrict__ outb, int nv)
{
    int i = blockIdx.x * blockDim.x + threadIdx.x;
    if (i >= nv) return;
    float4 v = ((const float4*)in)[i];
    int c = (i << 2) & 63;
    ushort4 o;
    o.x = __builtin_bit_cast(unsigned short, __float2bfloat16(fmaxf(v.x + bias[c + 0], 0.f)));
    o.y = __builtin_bit_cast(unsigned short, __float2bfloat16(fmaxf(v.y + bias[c + 1], 0.f)));
    o.z = __builtin_bit_cast(unsigned short, __float2bfloat16(fmaxf(v.z + bias[c + 2], 0.f)));
    o.w = __builtin_bit_cast(unsigned short, __float2bfloat16(fmaxf(v.w + bias[c + 3], 0.f)));
    ((ushort4*)outb)[i] = o;
}

// ---------------------------------------------------------------------------
// epi_full: thread-per-row, LDS-staged weights (broadcast reads), fully
// unrolled register arrays (no runtime indexing -> no scratch).
//   t = act(src); hx = t@Wout + bout -> hx_out; g = sigmoid(hx@Wg + bg);
//   gout = bf16(g*t)
// smode 0: src bf16 +bias+relu; 1: src f32 +bias+relu; 2: src f32 raw.
// N must be a multiple of 256 (it is: 1024..65536).
// ---------------------------------------------------------------------------
__global__ __launch_bounds__(256) void epi_full(
    const void* __restrict__ srcp, int smode, const float* __restrict__ bconv,
    const float* __restrict__ Wout, const float* __restrict__ bout,
    const float* __restrict__ Wg, const float* __restrict__ bg,
    float* __restrict__ hx_out, __hip_bfloat16* __restrict__ gout, int N)
{
    __shared__ float Woutl[64 * 32];
    __shared__ float Wgl[32 * 64];
    __shared__ float boutl[32];
    __shared__ float bgl[64];
    __shared__ float bcl[64];

    const int t = threadIdx.x;
    for (int i = t; i < 2048; i += 256) { Woutl[i] = Wout[i]; Wgl[i] = Wg[i]; }
    if (t < 32) boutl[t] = bout[t];
    if (t >= 64 && t < 128) bgl[t - 64] = bg[t - 64];
    if (t >= 128 && t < 192) bcl[t - 128] = bconv ? bconv[t - 128] : 0.f;
    __syncthreads();

    const int row = blockIdx.x * 256 + t;

    // ---- load t row into registers (64 values) ----
    float tv[64];
    if (smode == 0) {
        const ushort4* sb = (const ushort4*)((const __hip_bfloat16*)srcp + ((size_t)row << 6));
#pragma unroll
        for (int i = 0; i < 16; ++i) {
            ushort4 v = sb[i];
            tv[i * 4 + 0] = __bfloat162float(__builtin_bit_cast(__hip_bfloat16, v.x));
            tv[i * 4 + 1] = __bfloat162float(__builtin_bit_cast(__hip_bfloat16, v.y));
            tv[i * 4 + 2] = __bfloat162float(__builtin_bit_cast(__hip_bfloat16, v.z));
            tv[i * 4 + 3] = __bfloat162float(__builtin_bit_cast(__hip_bfloat16, v.w));
        }
    } else {
        const float4* sf = (const float4*)((const float*)srcp + ((size_t)row << 6));
#pragma unroll
        for (int i = 0; i < 16; ++i) {
            float4 v = sf[i];
            tv[i * 4 + 0] = v.x; tv[i * 4 + 1] = v.y;
            tv[i * 4 + 2] = v.z; tv[i * 4 + 3] = v.w;
        }
    }
    if (smode != 2) {
#pragma unroll
        for (int c = 0; c < 64; ++c) tv[c] = fmaxf(tv[c] + bcl[c], 0.f);
    }

    // ---- hx = t @ Wout + bout ----
    float hx[32];
#pragma unroll
    for (int d = 0; d < 32; ++d) hx[d] = boutl[d];
#pragma unroll
    for (int c = 0; c < 64; ++c) {
        float tc = tv[c];
        const f32x4* wr = (const f32x4*)&Woutl[c << 5];
#pragma unroll
        for (int d4 = 0; d4 < 8; ++d4) {
            f32x4 wv = wr[d4];
            hx[d4 * 4 + 0] = fmaf(tc, wv[0], hx[d4 * 4 + 0]);
            hx[d4 * 4 + 1] = fmaf(tc, wv[1], hx[d4 * 4 + 1]);
            hx[d4 * 4 + 2] = fmaf(tc, wv[2], hx[d4 * 4 + 2]);
            hx[d4 * 4 + 3] = fmaf(tc, wv[3], hx[d4 * 4 + 3]);
        }
    }
    {
        float* ho = hx_out + ((size_t)row << 5);
#pragma unroll
        for (int i = 0; i < 8; ++i) {
            float4 v = {hx[i * 4 + 0], hx[i * 4 + 1], hx[i * 4 + 2], hx[i * 4 + 3]};
            ((float4*)ho)[i] = v;
        }
    }

    // ---- g = sigmoid(hx @ Wg + bg); gout = bf16(g * t) ----
    __hip_bfloat16* go = gout + ((size_t)row << 6);
#pragma unroll
    for (int jc = 0; jc < 2; ++jc) {
        float acc[32];
#pragma unroll
        for (int jj = 0; jj < 32; ++jj) acc[jj] = bgl[jc * 32 + jj];
#pragma unroll
        for (int d = 0; d < 32; ++d) {
            float hd = hx[d];
            const f32x4* wr = (const f32x4*)&Wgl[(d << 6) + jc * 32];
#pragma unroll
            for (int j4 = 0; j4 < 8; ++j4) {
                f32x4 wv = wr[j4];
                acc[j4 * 4 + 0] = fmaf(hd, wv[0], acc[j4 * 4 + 0]);
                acc[j4 * 4 + 1] = fmaf(hd, wv[1], acc[j4 * 4 + 1]);
                acc[j4 * 4 + 2] = fmaf(hd, wv[2], acc[j4 * 4 + 2]);
                acc[j4 * 4 + 3] = fmaf(hd, wv[3], acc[j4 * 4 + 3]);
            }
        }
        unsigned short ob[32];
#pragma unroll
        for (int jj = 0; jj < 32; ++jj) {
            float gg = 1.f / (1.f + __expf(-acc[jj]));
            ob[jj] = __builtin_bit_cast(unsigned short,
                         __float2bfloat16(gg * tv[jc * 32 + jj]));
        }
#pragma unroll
        for (int i = 0; i < 8; ++i) {
            ushort4 v = {ob[i * 4 + 0], ob[i * 4 + 1], ob[i * 4 + 2], ob[i * 4 + 3]};
            ((ushort4*)go)[jc * 8 + i] = v;
        }
    }
}

// ---------------------------------------------------------------------------
extern "C" void kernel_launch(void* const* d_in, const int* in_sizes, int n_in,
                              void* d_out, int out_size, void* d_ws, size_t ws_size,
                              hipStream_t stream)
{
    const float* x    = (const float*)d_in[0];
    const float* Wg0  = (const float*)d_in[1];
    const float* bg0  = (const float*)d_in[2];
    const float* Wg1  = (const float*)d_in[3];
    const float* bg1  = (const float*)d_in[4];
    const float* Wout = (const float*)d_in[5];
    const float* bout = (const float*)d_in[6];
    const float* WA   = (const float*)d_in[7];
    const float* bA   = (const float*)d_in[8];
    const float* WB   = (const float*)d_in[9];
    const float* bB   = (const float*)d_in[10];
    const float* WD   = (const float*)d_in[11];
    const float* bD   = (const float*)d_in[12];
    const float* WC   = (const float*)d_in[13];
    const float* bC   = (const float*)d_in[14];
    const int* nmap[4] = {(const int*)d_in[15], (const int*)d_in[16],
                          (const int*)d_in[17], (const int*)d_in[18]};
    const int* ndm[3]  = {(const int*)d_in[19], (const int*)d_in[20],
                          (const int*)d_in[21]};

    float* out = (float*)d_out;
    __hip_bfloat16* featbf0 = (__hip_bfloat16*)d_ws;
    __hip_bfloat16* featbf1 = featbf0 + (size_t)N0 * 64;
    __hip_bfloat16* convbf  = featbf1 + (size_t)N0 * 64;
    float* conv32 = (float*)(convbf + (size_t)N0 * 64);
    __hip_bfloat16* WAt = (__hip_bfloat16*)(conv32 + (size_t)N2 * 64);
    __hip_bfloat16* WBt = WAt + 27 * 4096;
    __hip_bfloat16* WCt = WBt + 27 * 4096;
    __hip_bfloat16* WDt = WCt + 27 * 4096;

    const int Ns[4] = {N0, N1, N2, N3};
    size_t off[7];
    off[0] = 0;
    off[1] = off[0] + (size_t)N0 * 32;
    off[2] = off[1] + (size_t)N0 * 32;
    off[3] = off[2] + (size_t)N1 * 32;
    off[4] = off[3] + (size_t)N1 * 32;
    off[5] = off[4] + (size_t)N2 * 32;
    off[6] = off[5] + (size_t)N2 * 32;

    hipLaunchKernelGGL(prep_w4, dim3((89 * 4096 + 255) / 256), dim3(256), 0, stream,
                       WA, WB, WC, WD, WAt, 89 * 4096);

    auto run_conv = [&](const __hip_bfloat16* fin, const int* nm,
                        const __hip_bfloat16* Wt, int Nout, int K,
                        const float* bias2, void* bf_dst, int big_mode) -> int {
        if (Nout >= 16384) {
            hipLaunchKernelGGL(spconv_mfma, dim3(Nout / 64, 1), dim3(256), 0, stream,
                               fin, nm, Wt, bf_dst, bias2, Nout, K, big_mode);
            return 0;
        }
        int ch = (Nout == 4096) ? (K == 27 ? 4 : 2) : (K == 27 ? 7 : 4);
        hipMemsetAsync(conv32, 0, (size_t)Nout * 64 * sizeof(float), stream);
        hipLaunchKernelGGL(spconv_mfma, dim3(Nout / 64, ch), dim3(256), 0, stream,
                           fin, nm, Wt, conv32, (const float*)nullptr, Nout, K, 1);
        return 1;
    };

    // init: hx0 -> out0 ; featbf0 = bf16(sigmoid(hx0@Wg0+bg0) * x)
    hipLaunchKernelGGL(epi_full, dim3(N0 / 256), dim3(256), 0, stream,
                       (const void*)x, 2, (const float*)nullptr, Wout, bout, Wg0, bg0,
                       out + off[0], featbf0, N0);

    for (int s = 0; s < 3; ++s) {
        int N = Ns[s], Nn = Ns[s + 1];

        int mA = run_conv(featbf0, nmap[s], WAt, N, 27, bA, featbf1, 2);
        if (mA == 1)
            hipLaunchKernelGGL(epi_relu_bf, dim3((N * 16 + 255) / 256), dim3(256), 0, stream,
                               conv32, bA, featbf1, N * 16);
        int mB = run_conv(featbf1, nmap[s], WBt, N, 27, nullptr, convbf, 0);
        hipLaunchKernelGGL(epi_full, dim3(N / 256), dim3(256), 0, stream,
                           mB ? (const void*)conv32 : (const void*)convbf, mB, bB,
                           Wout, bout, Wg1, bg1, out + off[s * 2 + 1], featbf0, N);

        int mD = run_conv(featbf0, ndm[s], WDt, Nn, 8, bD, featbf1, 2);
        if (mD == 1)
            hipLaunchKernelGGL(epi_relu_bf, dim3((Nn * 16 + 255) / 256), dim3(256), 0, stream,
                               conv32, bD, featbf1, Nn * 16);
        int mC = run_conv(featbf1, nmap[s + 1], WCt, Nn, 27, nullptr, convbf, 0);
        hipLaunchKernelGGL(epi_full, dim3(Nn / 256), dim3(256), 0, stream,
                           mC ? (const void*)conv32 : (const void*)convbf, mC, bC,
                           Wout, bout, Wg0, bg0, out + off[s * 2 + 2], featbf0, Nn);
    }
}